// Round 23
// baseline (232.197 us; speedup 1.0000x reference)
//
#include <hip/hip_runtime.h>
#include <math.h>

#define B_    2
#define N_    2048
#define DIM_  1024
#define H_    16
#define D_    64
#define INNER_ 1024
#define QKVC_ 3072

typedef __attribute__((ext_vector_type(8))) short short8;
typedef __attribute__((ext_vector_type(4))) short short4v;
typedef __attribute__((ext_vector_type(4))) float f32x4;
typedef __attribute__((ext_vector_type(4))) float float4v;
typedef _Float16 half8 __attribute__((ext_vector_type(8)));
typedef __fp16 fp16v2 __attribute__((ext_vector_type(2)));

union h8u { short8 s; half8 h; fp16v2 h2[4]; };
static __device__ __forceinline__ half8 s2h(short8 s) { h8u u; u.s = s; return u.h; }

static __device__ __forceinline__ unsigned short f2h(float f) {
    _Float16 h = (_Float16)f;
    unsigned short u;
    __builtin_memcpy(&u, &h, 2);
    return u;
}
static __device__ __forceinline__ float h2f(unsigned short u) {
    _Float16 h;
    __builtin_memcpy(&h, &u, 2);
    return (float)h;
}

static __device__ __forceinline__ void gload16(const void* g, void* l) {
    __builtin_amdgcn_global_load_lds((__attribute__((address_space(1))) void*)(g),
                                     (__attribute__((address_space(3))) void*)(l),
                                     16, 0, 0);
}

// ---------------------------------------------------------------------------
// merged converts: blocks [0,2048) x->fp16; [2048,2816) w_qkv^T; [2816,3072) w_out^T
// ---------------------------------------------------------------------------
__global__ __launch_bounds__(256) void convert_all(const float* __restrict__ X,
                                                   const float* __restrict__ Wq,
                                                   const float* __restrict__ Wo,
                                                   unsigned short* __restrict__ Xh,
                                                   unsigned short* __restrict__ WqT,
                                                   unsigned short* __restrict__ WoT) {
    __shared__ unsigned short Sh[64][65];
    const int blk = blockIdx.x;
    const int tid = threadIdx.x;
    if (blk < 2048) {
        int t = blk * 256 + tid;
        size_t off = (size_t)t * 8;
        float4v a = *(const float4v*)(X + off);
        float4v b = *(const float4v*)(X + off + 4);
        short8 o;
#pragma unroll
        for (int j = 0; j < 4; ++j) {
            o[j]     = (short)f2h(a[j]);
            o[4 + j] = (short)f2h(b[j]);
        }
        *(short8*)(Xh + off) = o;
        return;
    }
    const float* W;
    unsigned short* T;
    int n0, k0, Nw;
    if (blk < 2816) {
        int g = blk - 2048;                 // 48 x 16
        W = Wq; T = WqT; Nw = QKVC_;
        n0 = (g % 48) * 64; k0 = (g / 48) * 64;
    } else {
        int g = blk - 2816;                 // 16 x 16
        W = Wo; T = WoT; Nw = DIM_;
        n0 = (g % 16) * 64; k0 = (g / 16) * 64;
    }
#pragma unroll
    for (int l = 0; l < 16; ++l) {
        int idx = tid + l * 256;
        int r = idx >> 6, c = idx & 63;
        Sh[c][r] = f2h(W[(size_t)(k0 + r) * Nw + n0 + c]);
    }
    __syncthreads();
#pragma unroll
    for (int l = 0; l < 16; ++l) {
        int idx = tid + l * 256;
        int r = idx >> 6, c = idx & 63;
        T[(size_t)(n0 + r) * 1024 + k0 + c] = Sh[r][c];
    }
}

// ---------------------------------------------------------------------------
// fp16 GEMM core, BK=64 (R20-proven): 128x128 tile, T2-swizzled LDS.
// ---------------------------------------------------------------------------
#define GEMM_STAGE64(gA, gB)                                                       \
    {                                                                              \
        int srow = lane >> 3;                                                      \
        int gsw  = ((lane & 7) ^ srow) * 8;                                        \
        _Pragma("unroll") for (int i_ = 0; i_ < 4; ++i_) {                         \
            gload16(gA + (size_t)(m0 + w * 32 + 8 * i_ + srow) * 1024 + k0 + gsw,  \
                    sA + (w * 32 + 8 * i_) * 64);                                  \
            gload16(gB + (size_t)(n0 + w * 32 + 8 * i_ + srow) * 1024 + k0 + gsw,  \
                    sB + (w * 32 + 8 * i_) * 64);                                  \
        }                                                                          \
    }

#define GEMM_BODY64()                                                              \
    half8 af[4][2], bf[4][2];                                                      \
    _Pragma("unroll") for (int f = 0; f < 4; ++f) {                                \
        int arow = (wr + f * 16 + (lane & 15)) * 64;                               \
        int brow = (wc + f * 16 + (lane & 15)) * 64;                               \
        _Pragma("unroll") for (int h = 0; h < 2; ++h) {                            \
            int g = (((lane >> 4) + 4 * h) ^ (lane & 7)) * 8;                      \
            af[f][h] = s2h(*(const short8*)&sA[arow + g]);                         \
            bf[f][h] = s2h(*(const short8*)&sB[brow + g]);                         \
        }                                                                          \
    }                                                                              \
    _Pragma("unroll") for (int i = 0; i < 4; ++i)                                  \
        _Pragma("unroll") for (int j = 0; j < 4; ++j) {                            \
            acc[i][j] = __builtin_amdgcn_mfma_f32_16x16x32_f16(af[i][0], bf[j][0], acc[i][j], 0, 0, 0); \
            acc[i][j] = __builtin_amdgcn_mfma_f32_16x16x32_f16(af[i][1], bf[j][1], acc[i][j], 0, 0, 0); \
        }

// XCD-aware bijective block remap (T1): nblk % 8 == 0 for both GEMM grids.
#define XCD_REMAP()                                                                \
    const int fblk = blockIdx.y * gridDim.x + blockIdx.x;                          \
    const int per_ = (gridDim.x * gridDim.y) >> 3;                                 \
    const int rf = (fblk & 7) * per_ + (fblk >> 3);                                \
    const int m0 = (rf / gridDim.x) * 128, n0 = (rf % gridDim.x) * 128;

// ---------------------------------------------------------------------------
// qkv GEMM with FUSED RoPE epilogue (native __sinf/__cosf only).
// ---------------------------------------------------------------------------
#define QSCALE 0.180336879963f   // 0.125 * log2(e)
__global__ __launch_bounds__(256) void qkv_gemm_mfma(const unsigned short* __restrict__ Ah,
                                                     const unsigned short* __restrict__ Bh,
                                                     unsigned short* __restrict__ Qh,
                                                     unsigned short* __restrict__ Kh,
                                                     unsigned short* __restrict__ Vh) {
    __shared__ __align__(16) unsigned short sA[8192], sB[8192];
    const int tid = threadIdx.x;
    const int lane = tid & 63, w = tid >> 6;
    const int wr = (w >> 1) * 64, wc = (w & 1) * 64;
    XCD_REMAP();
    f32x4 acc[4][4] = {};

    for (int k0 = 0; k0 < 1024; k0 += 64) {
        GEMM_STAGE64(Ah, Bh);
        __syncthreads();
        GEMM_BODY64();
        __syncthreads();
    }

    const int seg = n0 >> 10;            // whole block: 0=Q 1=K 2=V
    const int parity = lane & 1;

#pragma unroll
    for (int i = 0; i < 4; ++i) {
        int mbase = m0 + wr + i * 16 + (lane >> 4) * 4;
#pragma unroll
        for (int j = 0; j < 4; ++j) {
            int col = n0 + wc + j * 16 + (lane & 15);
            int wcol = col & 1023;
            int h = wcol >> 6, dd = wcol & 63;
            unsigned short* dst = (seg == 0) ? Qh : (seg == 1 ? Kh : Vh);
            if (seg == 2) {
#pragma unroll
                for (int r = 0; r < 4; ++r) {
                    int row = mbase + r;
                    int b = row >> 11, n = row & (N_ - 1);
                    dst[((size_t)(b * H_ + h) * N_ + n) * D_ + dd] = f2h(acc[i][j][r]);
                }
            } else {
                float freq = __builtin_amdgcn_exp2f((float)(dd >> 1) * -0.4152410118f);
#pragma unroll
                for (int r = 0; r < 4; ++r) {
                    int row = mbase + r;
                    int b = row >> 11, n = row & (N_ - 1);
                    float ang = (float)n * freq;
                    float s = __sinf(ang);
                    float c = __cosf(ang);
                    float val = acc[i][j][r];
                    float partner = __shfl_xor(val, 1);
                    float rot = parity ? (val * c + partner * s)
                                       : (val * c - partner * s);
                    if (seg == 0) rot *= QSCALE;
                    dst[((size_t)(b * H_ + h) * N_ + n) * D_ + dd] = f2h(rot);
                }
            }
        }
    }
}

// ---------------------------------------------------------------------------
// out projection GEMM, 128x64 tile (R22-proven; grid 16x32 = 2 blocks/CU).
// ---------------------------------------------------------------------------
__global__ __launch_bounds__(256) void out_gemm_mfma(const unsigned short* __restrict__ Ah,
                                                     const unsigned short* __restrict__ Bh,
                                                     const float* __restrict__ bias,
                                                     float* __restrict__ C) {
    __shared__ __align__(16) unsigned short sA[8192], sB[4096];
    const int tid = threadIdx.x;
    const int lane = tid & 63, w = tid >> 6;
    const int wr = w * 32;
    const int fblk = blockIdx.y * gridDim.x + blockIdx.x;
    const int per_ = (gridDim.x * gridDim.y) >> 3;
    const int rf = (fblk & 7) * per_ + (fblk >> 3);
    const int m0 = (rf / gridDim.x) * 128, n0 = (rf % gridDim.x) * 64;
    f32x4 acc[2][4] = {};

    for (int k0 = 0; k0 < 1024; k0 += 64) {
        {
            int srow = lane >> 3;
            int gsw  = ((lane & 7) ^ srow) * 8;
#pragma unroll
            for (int i_ = 0; i_ < 4; ++i_)
                gload16(Ah + (size_t)(m0 + w * 32 + 8 * i_ + srow) * 1024 + k0 + gsw,
                        sA + (w * 32 + 8 * i_) * 64);
            gload16(Bh + (size_t)(n0 + w * 8 + srow) * 1024 + k0 + gsw,
                    sB + (w * 8) * 64);
            gload16(Bh + (size_t)(n0 + 32 + w * 8 + srow) * 1024 + k0 + gsw,
                    sB + (32 + w * 8) * 64);
        }
        __syncthreads();
        {
            half8 af[2][2], bf[4][2];
#pragma unroll
            for (int f = 0; f < 2; ++f) {
                int arow = (wr + f * 16 + (lane & 15)) * 64;
#pragma unroll
                for (int h = 0; h < 2; ++h) {
                    int g = (((lane >> 4) + 4 * h) ^ (lane & 7)) * 8;
                    af[f][h] = s2h(*(const short8*)&sA[arow + g]);
                }
            }
#pragma unroll
            for (int j = 0; j < 4; ++j) {
                int brow = (j * 16 + (lane & 15)) * 64;
#pragma unroll
                for (int h = 0; h < 2; ++h) {
                    int g = (((lane >> 4) + 4 * h) ^ (lane & 7)) * 8;
                    bf[j][h] = s2h(*(const short8*)&sB[brow + g]);
                }
            }
#pragma unroll
            for (int i = 0; i < 2; ++i)
#pragma unroll
                for (int j = 0; j < 4; ++j) {
                    acc[i][j] = __builtin_amdgcn_mfma_f32_16x16x32_f16(af[i][0], bf[j][0], acc[i][j], 0, 0, 0);
                    acc[i][j] = __builtin_amdgcn_mfma_f32_16x16x32_f16(af[i][1], bf[j][1], acc[i][j], 0, 0, 0);
                }
        }
        __syncthreads();
    }

#pragma unroll
    for (int i = 0; i < 2; ++i) {
        int mbase = m0 + wr + i * 16 + (lane >> 4) * 4;
#pragma unroll
        for (int j = 0; j < 4; ++j) {
            int col = n0 + j * 16 + (lane & 15);
            float bv = bias[col];
#pragma unroll
            for (int r = 0; r < 4; ++r)
                C[(size_t)(mbase + r) * DIM_ + col] = acc[i][j][r] + bv;
        }
    }
}

// ---------------------------------------------------------------------------
// Flash attention v12 = v11 + SPLIT-KV (2 halves, 512 blocks = 2/CU = 32
// waves/CU). Static-shift softmax makes halves combinable by pure addition:
// each block writes UNNORMALIZED O (fp16) and per-q lsum (fp32); a combine
// kernel computes (O0+O1)/(l0+l1). Core loop identical to v11, range
// [t0, t0+NTH). Waves 0-7 stage.
// ---------------------------------------------------------------------------
#define PADV 72
#define NT   (N_ / 64)
#define NTH  (NT / 2)
__global__ __launch_bounds__(1024, 2) void attn_mfma(const unsigned short* __restrict__ Qh,
                                                     const unsigned short* __restrict__ Kh,
                                                     const unsigned short* __restrict__ Vh,
                                                     unsigned short* __restrict__ O0h,
                                                     unsigned short* __restrict__ O1h,
                                                     float* __restrict__ L0,
                                                     float* __restrict__ L1) {
    __shared__ __align__(16) unsigned short Ks[2 * 64 * 64];    // K rows, XOR-swz cols
    __shared__ __align__(16) unsigned short Vt[3][64][PADV];    // permuted V^T ring
    const int tid = threadIdx.x;
    const int w = tid >> 6;          // 0..15
    const int l = tid & 63;
    const int lr = l & 15, lg = l >> 4;
    const bool stager = (tid < 512);

    // remap: 512 blocks -> (xcd, bh, qtile, half)
    const int f = blockIdx.y * gridDim.x + blockIdx.x;          // 0..511
    const int x = f & 7, g = f >> 3;                            // g: 0..63
    const int bh = x * 4 + (g >> 4);
    const int rem = g & 15;
    const int q0 = (rem >> 1) * 256;
    const int half = rem & 1;
    const int t0 = half * NTH;
    const size_t base = (size_t)bh * N_ * D_;
    unsigned short* Ohalf = half ? O1h : O0h;
    float* Lh = half ? L1 : L0;

    // K staging coords (threads 0-511; pre-swizzled source, linear LDS dest)
    const int srow = tid >> 3;           // 0..63 (for tid<512)
    const int scg  = tid & 7;
    const int gcg  = scg ^ (srow & 7);
    const unsigned short* ksrc = Kh + base + (size_t)srow * D_ + gcg * 8;
    unsigned short* kdst = Ks + w * 512; // valid for w<8

    // K fragment LDS offsets (loop-invariant)
    const int kb0 = lr * 64 + (lg ^ (lr & 7)) * 8;
    const int kb1 = lr * 64 + ((lg + 4) ^ (lr & 7)) * 8;

    // V staging coords (threads 0-511) + permuted column position
    const int sd0 = (tid & 15) * 4;
    const int skv = ((tid >> 4) & 31) * 2;
    const int vpos = ((skv >> 5) * 32) + (((skv >> 2) & 3) * 8) +
                     (((skv >> 4) & 1) * 4) + (skv & 3);

    // Q as B-operand: rows q0 + w*16 + lr
    const unsigned short* qrow = Qh + base + (size_t)(q0 + w * 16 + lr) * D_ + lg * 8;
    const half8 qf0 = s2h(*(const short8*)qrow);
    const half8 qf1 = s2h(*(const short8*)(qrow + 32));

    f32x4 oacc[4] = {};                 // [dt]: q=lg*4+r, d=dt*16+lr
    float lsum = 0.f;                   // per-lane partial lsum
    h8u pa_prev[2];                     // carried P fragments (tile ti-1)
    pa_prev[0].s = short8{0,0,0,0,0,0,0,0};
    pa_prev[1].s = short8{0,0,0,0,0,0,0,0};

    // ---- prologue: stage tile t0 (waves 0-7) ----
    if (stager) {
        gload16(ksrc + (size_t)t0 * 64 * D_, kdst);
        short4v r0 = *(const short4v*)(Vh + base + (size_t)(t0 * 64 + skv + 0) * D_ + sd0);
        short4v r1 = *(const short4v*)(Vh + base + (size_t)(t0 * 64 + skv + 1) * D_ + sd0);
#pragma unroll
        for (int j = 0; j < 4; ++j) {
            unsigned int pk = (unsigned int)(unsigned short)r0[j] |
                              ((unsigned int)(unsigned short)r1[j] << 16);
            *(unsigned int*)&Vt[0][sd0 + j][vpos] = pk;
        }
    }

    int rd = 2, cu = 0, wr_ = 1;        // V ring slots: (ti-1)%3, ti%3, (ti+1)%3

    for (int it = 0; it < NTH; ++it) {
        const int ti = t0 + it;
        const int kcur = it & 1, knxt = kcur ^ 1;
        __syncthreads();

        // ---- issue tile ti+1 staging early (waves 0-7) ----
        short4v n0v = {}, n1v = {};
        if (stager && it + 1 < NTH) {
            gload16(ksrc + (size_t)(ti + 1) * 64 * D_, kdst + knxt * 4096);
            const unsigned short* nsrc = Vh + base + (size_t)((ti + 1) * 64 + skv) * D_ + sd0;
            n0v = *(const short4v*)nsrc;
            n1v = *(const short4v*)(nsrc + D_);
        }

        // ---- MFMA cluster: QK(ti) then PV(ti-1) ----
        f32x4 sacc[4] = {};
        const unsigned short* kbuf = Ks + kcur * 4096;
        __builtin_amdgcn_s_setprio(1);
#pragma unroll
        for (int t = 0; t < 4; ++t) {
            half8 kf0 = s2h(*(const short8*)(kbuf + t * 1024 + kb0));
            half8 kf1 = s2h(*(const short8*)(kbuf + t * 1024 + kb1));
            sacc[t] = __builtin_amdgcn_mfma_f32_16x16x32_f16(kf0, qf0, sacc[t], 0, 0, 0);
            sacc[t] = __builtin_amdgcn_mfma_f32_16x16x32_f16(kf1, qf1, sacc[t], 0, 0, 0);
        }
        if (it > 0) {
#pragma unroll
            for (int m2 = 0; m2 < 2; ++m2)
#pragma unroll
                for (int dt = 0; dt < 4; ++dt) {
                    half8 vf = s2h(*(const short8*)&Vt[rd][dt * 16 + lr][m2 * 32 + lg * 8]);
                    oacc[dt] = __builtin_amdgcn_mfma_f32_16x16x32_f16(pa_prev[m2].h, vf, oacc[dt], 0, 0, 0);
                }
        }
        __builtin_amdgcn_s_setprio(0);

        // ---- softmax(ti): static shift — P = exp2(s) directly ----
#pragma unroll
        for (int t = 0; t < 4; ++t) {
            float e0 = __builtin_amdgcn_exp2f(sacc[t][0]);
            float e1 = __builtin_amdgcn_exp2f(sacc[t][1]);
            float e2 = __builtin_amdgcn_exp2f(sacc[t][2]);
            float e3 = __builtin_amdgcn_exp2f(sacc[t][3]);
            lsum += (e0 + e1) + (e2 + e3);
            pa_prev[t >> 1].h2[(t & 1) * 2]     = __builtin_amdgcn_cvt_pkrtz(e0, e1);
            pa_prev[t >> 1].h2[(t & 1) * 2 + 1] = __builtin_amdgcn_cvt_pkrtz(e2, e3);
        }

        // ---- commit V(ti+1) into ring slot wr_ (waves 0-7) ----
        if (stager && it + 1 < NTH) {
#pragma unroll
            for (int j = 0; j < 4; ++j) {
                unsigned int pk = (unsigned int)(unsigned short)n0v[j] |
                                  ((unsigned int)(unsigned short)n1v[j] << 16);
                *(unsigned int*)&Vt[wr_][sd0 + j][vpos] = pk;
            }
        }
        int t_ = rd; rd = cu; cu = wr_; wr_ = t_;
    }

    // ---- epilogue: final PV, write UNNORMALIZED O + lsum ----
#pragma unroll
    for (int m2 = 0; m2 < 2; ++m2)
#pragma unroll
        for (int dt = 0; dt < 4; ++dt) {
            half8 vf = s2h(*(const short8*)&Vt[rd][dt * 16 + lr][m2 * 32 + lg * 8]);
            oacc[dt] = __builtin_amdgcn_mfma_f32_16x16x32_f16(pa_prev[m2].h, vf, oacc[dt], 0, 0, 0);
        }

    lsum += __shfl_xor(lsum, 16);
    lsum += __shfl_xor(lsum, 32);
    if (lg == 0)
        Lh[(size_t)bh * N_ + q0 + w * 16 + lr] = lsum;

    int b = bh >> 4, h = bh & 15;
#pragma unroll
    for (int r = 0; r < 4; ++r) {
        size_t orow = ((size_t)b * N_ + q0 + w * 16 + lg * 4 + r) * INNER_ + h * 64 + lr;
#pragma unroll
        for (int dt = 0; dt < 4; ++dt)
            Ohalf[orow + 16 * dt] = f2h(oacc[dt][r]);
    }
}

// ---------------------------------------------------------------------------
// combine: Oh = (O0 + O1) / (l0 + l1). 8 elems/thread; d-groups of 8 share h.
// ---------------------------------------------------------------------------
__global__ __launch_bounds__(256) void attn_combine(const unsigned short* __restrict__ O0h,
                                                    const unsigned short* __restrict__ O1h,
                                                    const float* __restrict__ L0,
                                                    const float* __restrict__ L1,
                                                    unsigned short* __restrict__ Oh) {
    int t = blockIdx.x * blockDim.x + threadIdx.x;
    size_t e = (size_t)t * 8;
    int row = (int)(e >> 10);            // b*N + n
    int col = (int)(e & 1023);
    int h = col >> 6;
    int b = row >> 11, n = row & (N_ - 1);
    size_t lidx = (size_t)(b * H_ + h) * N_ + n;
    float inv = 1.0f / (L0[lidx] + L1[lidx]);
    short8 a = *(const short8*)(O0h + e);
    short8 c = *(const short8*)(O1h + e);
    short8 o;
#pragma unroll
    for (int j = 0; j < 8; ++j)
        o[j] = (short)f2h((h2f((unsigned short)a[j]) + h2f((unsigned short)c[j])) * inv);
    *(short8*)(Oh + e) = o;
}

// ---------------------------------------------------------------------------
extern "C" void kernel_launch(void* const* d_in, const int* in_sizes, int n_in,
                              void* d_out, int out_size, void* d_ws, size_t ws_size,
                              hipStream_t stream) {
    const float* x     = (const float*)d_in[0];
    const float* w_qkv = (const float*)d_in[1];
    const float* w_out = (const float*)d_in[2];
    const float* b_out = (const float*)d_in[3];
    float* out = (float*)d_out;

    unsigned short* Xh  = (unsigned short*)d_ws;     // 4M elems (reused as Oh)
    unsigned short* WqT = Xh + 4194304;              // 3M
    unsigned short* WoT = WqT + 3145728;             // 1M
    unsigned short* Qh  = WoT + 1048576;             // 4M
    unsigned short* Kh  = Qh + 4194304;              // 4M
    unsigned short* Vh  = Kh + 4194304;              // 4M
    unsigned short* O0h = Vh + 4194304;              // 4M
    unsigned short* O1h = O0h + 4194304;             // 4M
    float* L0 = (float*)(O1h + 4194304);             // 64K floats
    float* L1 = L0 + 65536;                          // 64K floats

    convert_all<<<dim3(3072), 256, 0, stream>>>(x, w_qkv, w_out, Xh, WqT, WoT);
    qkv_gemm_mfma<<<dim3(QKVC_ / 128, 32), 256, 0, stream>>>(Xh, WqT, Qh, Kh, Vh);
    attn_mfma<<<dim3(16, 32), 1024, 0, stream>>>(Qh, Kh, Vh, O0h, O1h, L0, L1);
    attn_combine<<<dim3(2048), 256, 0, stream>>>(O0h, O1h, L0, L1, Xh);
    out_gemm_mfma<<<dim3(DIM_ / 64, 32), 256, 0, stream>>>(Xh, WoT, b_out, out);
}

// Round 24
// 124.411 us; speedup vs baseline: 1.8664x; 1.8664x over previous
//
#include <hip/hip_runtime.h>
#include <math.h>

#define B_    2
#define N_    2048
#define DIM_  1024
#define H_    16
#define D_    64
#define INNER_ 1024
#define QKVC_ 3072

typedef __attribute__((ext_vector_type(8))) short short8;
typedef __attribute__((ext_vector_type(4))) short short4v;
typedef __attribute__((ext_vector_type(4))) float f32x4;
typedef __attribute__((ext_vector_type(4))) float float4v;
typedef _Float16 half8 __attribute__((ext_vector_type(8)));
typedef __fp16 fp16v2 __attribute__((ext_vector_type(2)));

union h8u { short8 s; half8 h; fp16v2 h2[4]; };
static __device__ __forceinline__ half8 s2h(short8 s) { h8u u; u.s = s; return u.h; }

static __device__ __forceinline__ unsigned short f2h(float f) {
    _Float16 h = (_Float16)f;
    unsigned short u;
    __builtin_memcpy(&u, &h, 2);
    return u;
}
static __device__ __forceinline__ float h2f(unsigned short u) {
    _Float16 h;
    __builtin_memcpy(&h, &u, 2);
    return (float)h;
}

static __device__ __forceinline__ void gload16(const void* g, void* l) {
    __builtin_amdgcn_global_load_lds((__attribute__((address_space(1))) void*)(g),
                                     (__attribute__((address_space(3))) void*)(l),
                                     16, 0, 0);
}

// ---------------------------------------------------------------------------
// merged converts: blocks [0,2048) x->fp16; [2048,2816) w_qkv^T; [2816,3072) w_out^T
// ---------------------------------------------------------------------------
__global__ __launch_bounds__(256) void convert_all(const float* __restrict__ X,
                                                   const float* __restrict__ Wq,
                                                   const float* __restrict__ Wo,
                                                   unsigned short* __restrict__ Xh,
                                                   unsigned short* __restrict__ WqT,
                                                   unsigned short* __restrict__ WoT) {
    __shared__ unsigned short Sh[64][65];
    const int blk = blockIdx.x;
    const int tid = threadIdx.x;
    if (blk < 2048) {
        int t = blk * 256 + tid;
        size_t off = (size_t)t * 8;
        float4v a = *(const float4v*)(X + off);
        float4v b = *(const float4v*)(X + off + 4);
        short8 o;
#pragma unroll
        for (int j = 0; j < 4; ++j) {
            o[j]     = (short)f2h(a[j]);
            o[4 + j] = (short)f2h(b[j]);
        }
        *(short8*)(Xh + off) = o;
        return;
    }
    const float* W;
    unsigned short* T;
    int n0, k0, Nw;
    if (blk < 2816) {
        int g = blk - 2048;                 // 48 x 16
        W = Wq; T = WqT; Nw = QKVC_;
        n0 = (g % 48) * 64; k0 = (g / 48) * 64;
    } else {
        int g = blk - 2816;                 // 16 x 16
        W = Wo; T = WoT; Nw = DIM_;
        n0 = (g % 16) * 64; k0 = (g / 16) * 64;
    }
#pragma unroll
    for (int l = 0; l < 16; ++l) {
        int idx = tid + l * 256;
        int r = idx >> 6, c = idx & 63;
        Sh[c][r] = f2h(W[(size_t)(k0 + r) * Nw + n0 + c]);
    }
    __syncthreads();
#pragma unroll
    for (int l = 0; l < 16; ++l) {
        int idx = tid + l * 256;
        int r = idx >> 6, c = idx & 63;
        T[(size_t)(n0 + r) * 1024 + k0 + c] = Sh[r][c];
    }
}

// ---------------------------------------------------------------------------
// fp16 GEMM core, BK=64 (R20-proven): 128x128 tile, T2-swizzled LDS.
// ---------------------------------------------------------------------------
#define GEMM_STAGE64(gA, gB)                                                       \
    {                                                                              \
        int srow = lane >> 3;                                                      \
        int gsw  = ((lane & 7) ^ srow) * 8;                                        \
        _Pragma("unroll") for (int i_ = 0; i_ < 4; ++i_) {                         \
            gload16(gA + (size_t)(m0 + w * 32 + 8 * i_ + srow) * 1024 + k0 + gsw,  \
                    sA + (w * 32 + 8 * i_) * 64);                                  \
            gload16(gB + (size_t)(n0 + w * 32 + 8 * i_ + srow) * 1024 + k0 + gsw,  \
                    sB + (w * 32 + 8 * i_) * 64);                                  \
        }                                                                          \
    }

#define GEMM_BODY64()                                                              \
    half8 af[4][2], bf[4][2];                                                      \
    _Pragma("unroll") for (int f = 0; f < 4; ++f) {                                \
        int arow = (wr + f * 16 + (lane & 15)) * 64;                               \
        int brow = (wc + f * 16 + (lane & 15)) * 64;                               \
        _Pragma("unroll") for (int h = 0; h < 2; ++h) {                            \
            int g = (((lane >> 4) + 4 * h) ^ (lane & 7)) * 8;                      \
            af[f][h] = s2h(*(const short8*)&sA[arow + g]);                         \
            bf[f][h] = s2h(*(const short8*)&sB[brow + g]);                         \
        }                                                                          \
    }                                                                              \
    _Pragma("unroll") for (int i = 0; i < 4; ++i)                                  \
        _Pragma("unroll") for (int j = 0; j < 4; ++j) {                            \
            acc[i][j] = __builtin_amdgcn_mfma_f32_16x16x32_f16(af[i][0], bf[j][0], acc[i][j], 0, 0, 0); \
            acc[i][j] = __builtin_amdgcn_mfma_f32_16x16x32_f16(af[i][1], bf[j][1], acc[i][j], 0, 0, 0); \
        }

// XCD-aware bijective block remap (T1): nblk % 8 == 0 for both GEMM grids.
#define XCD_REMAP()                                                                \
    const int fblk = blockIdx.y * gridDim.x + blockIdx.x;                          \
    const int per_ = (gridDim.x * gridDim.y) >> 3;                                 \
    const int rf = (fblk & 7) * per_ + (fblk >> 3);                                \
    const int m0 = (rf / gridDim.x) * 128, n0 = (rf % gridDim.x) * 128;

// ---------------------------------------------------------------------------
// qkv GEMM with FUSED RoPE epilogue (native __sinf/__cosf only).
// ---------------------------------------------------------------------------
#define QSCALE 0.180336879963f   // 0.125 * log2(e)
__global__ __launch_bounds__(256) void qkv_gemm_mfma(const unsigned short* __restrict__ Ah,
                                                     const unsigned short* __restrict__ Bh,
                                                     unsigned short* __restrict__ Qh,
                                                     unsigned short* __restrict__ Kh,
                                                     unsigned short* __restrict__ Vh) {
    __shared__ __align__(16) unsigned short sA[8192], sB[8192];
    const int tid = threadIdx.x;
    const int lane = tid & 63, w = tid >> 6;
    const int wr = (w >> 1) * 64, wc = (w & 1) * 64;
    XCD_REMAP();
    f32x4 acc[4][4] = {};

    for (int k0 = 0; k0 < 1024; k0 += 64) {
        GEMM_STAGE64(Ah, Bh);
        __syncthreads();
        GEMM_BODY64();
        __syncthreads();
    }

    const int seg = n0 >> 10;            // whole block: 0=Q 1=K 2=V
    const int parity = lane & 1;

#pragma unroll
    for (int i = 0; i < 4; ++i) {
        int mbase = m0 + wr + i * 16 + (lane >> 4) * 4;
#pragma unroll
        for (int j = 0; j < 4; ++j) {
            int col = n0 + wc + j * 16 + (lane & 15);
            int wcol = col & 1023;
            int h = wcol >> 6, dd = wcol & 63;
            unsigned short* dst = (seg == 0) ? Qh : (seg == 1 ? Kh : Vh);
            if (seg == 2) {
#pragma unroll
                for (int r = 0; r < 4; ++r) {
                    int row = mbase + r;
                    int b = row >> 11, n = row & (N_ - 1);
                    dst[((size_t)(b * H_ + h) * N_ + n) * D_ + dd] = f2h(acc[i][j][r]);
                }
            } else {
                float freq = __builtin_amdgcn_exp2f((float)(dd >> 1) * -0.4152410118f);
#pragma unroll
                for (int r = 0; r < 4; ++r) {
                    int row = mbase + r;
                    int b = row >> 11, n = row & (N_ - 1);
                    float ang = (float)n * freq;
                    float s = __sinf(ang);
                    float c = __cosf(ang);
                    float val = acc[i][j][r];
                    float partner = __shfl_xor(val, 1);
                    float rot = parity ? (val * c + partner * s)
                                       : (val * c - partner * s);
                    if (seg == 0) rot *= QSCALE;
                    dst[((size_t)(b * H_ + h) * N_ + n) * D_ + dd] = f2h(rot);
                }
            }
        }
    }
}

// ---------------------------------------------------------------------------
// out projection GEMM, 128x64 tile (R22-proven; grid 16x32 = 2 blocks/CU).
// ---------------------------------------------------------------------------
__global__ __launch_bounds__(256) void out_gemm_mfma(const unsigned short* __restrict__ Ah,
                                                     const unsigned short* __restrict__ Bh,
                                                     const float* __restrict__ bias,
                                                     float* __restrict__ C) {
    __shared__ __align__(16) unsigned short sA[8192], sB[4096];
    const int tid = threadIdx.x;
    const int lane = tid & 63, w = tid >> 6;
    const int wr = w * 32;
    const int fblk = blockIdx.y * gridDim.x + blockIdx.x;
    const int per_ = (gridDim.x * gridDim.y) >> 3;
    const int rf = (fblk & 7) * per_ + (fblk >> 3);
    const int m0 = (rf / gridDim.x) * 128, n0 = (rf % gridDim.x) * 64;
    f32x4 acc[2][4] = {};

    for (int k0 = 0; k0 < 1024; k0 += 64) {
        {
            int srow = lane >> 3;
            int gsw  = ((lane & 7) ^ srow) * 8;
#pragma unroll
            for (int i_ = 0; i_ < 4; ++i_)
                gload16(Ah + (size_t)(m0 + w * 32 + 8 * i_ + srow) * 1024 + k0 + gsw,
                        sA + (w * 32 + 8 * i_) * 64);
            gload16(Bh + (size_t)(n0 + w * 8 + srow) * 1024 + k0 + gsw,
                    sB + (w * 8) * 64);
            gload16(Bh + (size_t)(n0 + 32 + w * 8 + srow) * 1024 + k0 + gsw,
                    sB + (32 + w * 8) * 64);
        }
        __syncthreads();
        {
            half8 af[2][2], bf[4][2];
#pragma unroll
            for (int f = 0; f < 2; ++f) {
                int arow = (wr + f * 16 + (lane & 15)) * 64;
#pragma unroll
                for (int h = 0; h < 2; ++h) {
                    int g = (((lane >> 4) + 4 * h) ^ (lane & 7)) * 8;
                    af[f][h] = s2h(*(const short8*)&sA[arow + g]);
                }
            }
#pragma unroll
            for (int j = 0; j < 4; ++j) {
                int brow = (j * 16 + (lane & 15)) * 64;
#pragma unroll
                for (int h = 0; h < 2; ++h) {
                    int g = (((lane >> 4) + 4 * h) ^ (lane & 7)) * 8;
                    bf[j][h] = s2h(*(const short8*)&sB[brow + g]);
                }
            }
#pragma unroll
            for (int i = 0; i < 2; ++i)
#pragma unroll
                for (int j = 0; j < 4; ++j) {
                    acc[i][j] = __builtin_amdgcn_mfma_f32_16x16x32_f16(af[i][0], bf[j][0], acc[i][j], 0, 0, 0);
                    acc[i][j] = __builtin_amdgcn_mfma_f32_16x16x32_f16(af[i][1], bf[j][1], acc[i][j], 0, 0, 0);
                }
        }
        __syncthreads();
    }

#pragma unroll
    for (int i = 0; i < 2; ++i) {
        int mbase = m0 + wr + i * 16 + (lane >> 4) * 4;
#pragma unroll
        for (int j = 0; j < 4; ++j) {
            int col = n0 + j * 16 + (lane & 15);
            float bv = bias[col];
#pragma unroll
            for (int r = 0; r < 4; ++r)
                C[(size_t)(mbase + r) * DIM_ + col] = acc[i][j][r] + bv;
        }
    }
}

// ---------------------------------------------------------------------------
// Flash attention v12b: SPLIT-KV on the v7 geometry (512 threads, 8 waves,
// q-tile 128). Grid 1024 blocks = 32bh x 16qtile x 2half -> 3 blocks/CU
// (LDS-bound) = 24 waves/CU. launch_bounds(512,6): VGPR cap ~85, no spill
// (R23 failure was the 64-VGPR cap of (1024,2) forcing scratch).
// Static-shift softmax -> halves combine by pure addition: block writes
// UNNORMALIZED O (fp16) + per-q lsum (fp32); combine kernel divides.
// ---------------------------------------------------------------------------
#define PADV 72
#define NT   (N_ / 64)
#define NTH  (NT / 2)
__global__ __launch_bounds__(512, 6) void attn_mfma(const unsigned short* __restrict__ Qh,
                                                    const unsigned short* __restrict__ Kh,
                                                    const unsigned short* __restrict__ Vh,
                                                    unsigned short* __restrict__ O0h,
                                                    unsigned short* __restrict__ O1h,
                                                    float* __restrict__ L0,
                                                    float* __restrict__ L1) {
    __shared__ __align__(16) unsigned short Ks[2 * 64 * 64];    // K rows, XOR-swz cols
    __shared__ __align__(16) unsigned short Vt[3][64][PADV];    // permuted V^T ring
    const int tid = threadIdx.x;
    const int w = tid >> 6;          // 0..7
    const int l = tid & 63;
    const int lr = l & 15, lg = l >> 4;

    // remap: 1024 blocks -> (xcd, bh, qtile, half)
    const int f = blockIdx.y * gridDim.x + blockIdx.x;          // 0..1023
    const int x = f & 7, g = f >> 3;                            // g: 0..127
    const int bh = x * 4 + (g >> 5);
    const int rem = g & 31;
    const int q0 = (rem >> 1) * 128;
    const int half = rem & 1;
    const int t0 = half * NTH;
    const size_t base = (size_t)bh * N_ * D_;
    unsigned short* Ohalf = half ? O1h : O0h;
    float* Lh = half ? L1 : L0;

    // K staging coords (pre-swizzled global source, linear LDS dest)
    const int srow = tid >> 3;           // 0..63
    const int scg  = tid & 7;
    const int gcg  = scg ^ (srow & 7);
    const unsigned short* ksrc = Kh + base + (size_t)srow * D_ + gcg * 8;
    unsigned short* kdst = Ks + w * 512;

    // K fragment LDS offsets (loop-invariant)
    const int kb0 = lr * 64 + (lg ^ (lr & 7)) * 8;
    const int kb1 = lr * 64 + ((lg + 4) ^ (lr & 7)) * 8;

    // V staging coords + permuted column position
    const int sd0 = (tid & 15) * 4;
    const int skv = (tid >> 4) * 2;
    const int vpos = ((skv >> 5) * 32) + (((skv >> 2) & 3) * 8) +
                     (((skv >> 4) & 1) * 4) + (skv & 3);

    // Q as B-operand: rows q0 + w*16 + lr
    const unsigned short* qrow = Qh + base + (size_t)(q0 + w * 16 + lr) * D_ + lg * 8;
    const half8 qf0 = s2h(*(const short8*)qrow);
    const half8 qf1 = s2h(*(const short8*)(qrow + 32));

    f32x4 oacc[4] = {};                 // [dt]: q=lg*4+r, d=dt*16+lr
    float lsum = 0.f;                   // per-lane partial lsum
    h8u pa_prev[2];                     // carried P fragments (tile ti-1)
    pa_prev[0].s = short8{0,0,0,0,0,0,0,0};
    pa_prev[1].s = short8{0,0,0,0,0,0,0,0};

    // ---- prologue: stage tile t0 (K buf 0, V ring slot 0) ----
    gload16(ksrc + (size_t)t0 * 64 * D_, kdst);
    {
        short4v r0 = *(const short4v*)(Vh + base + (size_t)(t0 * 64 + skv + 0) * D_ + sd0);
        short4v r1 = *(const short4v*)(Vh + base + (size_t)(t0 * 64 + skv + 1) * D_ + sd0);
#pragma unroll
        for (int j = 0; j < 4; ++j) {
            unsigned int pk = (unsigned int)(unsigned short)r0[j] |
                              ((unsigned int)(unsigned short)r1[j] << 16);
            *(unsigned int*)&Vt[0][sd0 + j][vpos] = pk;
        }
    }

    int rd = 2, cu = 0, wr_ = 1;        // V ring slots: (it-1)%3, it%3, (it+1)%3

    for (int it = 0; it < NTH; ++it) {
        const int ti = t0 + it;
        const int kcur = it & 1, knxt = kcur ^ 1;
        __syncthreads();

        // ---- issue tile ti+1 staging early ----
        short4v n0v = {}, n1v = {};
        if (it + 1 < NTH) {
            gload16(ksrc + (size_t)(ti + 1) * 64 * D_, kdst + knxt * 4096);
            const unsigned short* nsrc = Vh + base + (size_t)((ti + 1) * 64 + skv) * D_ + sd0;
            n0v = *(const short4v*)nsrc;
            n1v = *(const short4v*)(nsrc + D_);
        }

        // ---- MFMA cluster: QK(ti) then PV(ti-1) ----
        f32x4 sacc[4] = {};
        const unsigned short* kbuf = Ks + kcur * 4096;
        __builtin_amdgcn_s_setprio(1);
#pragma unroll
        for (int t = 0; t < 4; ++t) {
            half8 kf0 = s2h(*(const short8*)(kbuf + t * 1024 + kb0));
            half8 kf1 = s2h(*(const short8*)(kbuf + t * 1024 + kb1));
            sacc[t] = __builtin_amdgcn_mfma_f32_16x16x32_f16(kf0, qf0, sacc[t], 0, 0, 0);
            sacc[t] = __builtin_amdgcn_mfma_f32_16x16x32_f16(kf1, qf1, sacc[t], 0, 0, 0);
        }
        if (it > 0) {
#pragma unroll
            for (int m2 = 0; m2 < 2; ++m2)
#pragma unroll
                for (int dt = 0; dt < 4; ++dt) {
                    half8 vf = s2h(*(const short8*)&Vt[rd][dt * 16 + lr][m2 * 32 + lg * 8]);
                    oacc[dt] = __builtin_amdgcn_mfma_f32_16x16x32_f16(pa_prev[m2].h, vf, oacc[dt], 0, 0, 0);
                }
        }
        __builtin_amdgcn_s_setprio(0);

        // ---- softmax(ti): static shift — P = exp2(s) directly ----
#pragma unroll
        for (int t = 0; t < 4; ++t) {
            float e0 = __builtin_amdgcn_exp2f(sacc[t][0]);
            float e1 = __builtin_amdgcn_exp2f(sacc[t][1]);
            float e2 = __builtin_amdgcn_exp2f(sacc[t][2]);
            float e3 = __builtin_amdgcn_exp2f(sacc[t][3]);
            lsum += (e0 + e1) + (e2 + e3);
            pa_prev[t >> 1].h2[(t & 1) * 2]     = __builtin_amdgcn_cvt_pkrtz(e0, e1);
            pa_prev[t >> 1].h2[(t & 1) * 2 + 1] = __builtin_amdgcn_cvt_pkrtz(e2, e3);
        }

        // ---- commit V(ti+1) into ring slot wr_ ----
        if (it + 1 < NTH) {
#pragma unroll
            for (int j = 0; j < 4; ++j) {
                unsigned int pk = (unsigned int)(unsigned short)n0v[j] |
                                  ((unsigned int)(unsigned short)n1v[j] << 16);
                *(unsigned int*)&Vt[wr_][sd0 + j][vpos] = pk;
            }
        }
        int t_ = rd; rd = cu; cu = wr_; wr_ = t_;
    }

    // ---- epilogue: final PV, write UNNORMALIZED O + lsum ----
#pragma unroll
    for (int m2 = 0; m2 < 2; ++m2)
#pragma unroll
        for (int dt = 0; dt < 4; ++dt) {
            half8 vf = s2h(*(const short8*)&Vt[rd][dt * 16 + lr][m2 * 32 + lg * 8]);
            oacc[dt] = __builtin_amdgcn_mfma_f32_16x16x32_f16(pa_prev[m2].h, vf, oacc[dt], 0, 0, 0);
        }

    lsum += __shfl_xor(lsum, 16);
    lsum += __shfl_xor(lsum, 32);
    if (lg == 0)
        Lh[(size_t)bh * N_ + q0 + w * 16 + lr] = lsum;

    int b = bh >> 4, h = bh & 15;
#pragma unroll
    for (int r = 0; r < 4; ++r) {
        size_t orow = ((size_t)b * N_ + q0 + w * 16 + lg * 4 + r) * INNER_ + h * 64 + lr;
#pragma unroll
        for (int dt = 0; dt < 4; ++dt)
            Ohalf[orow + 16 * dt] = f2h(oacc[dt][r]);
    }
}

// ---------------------------------------------------------------------------
// combine: Oh = (O0 + O1) / (l0 + l1). 8 elems/thread; d-groups of 8 share h.
// ---------------------------------------------------------------------------
__global__ __launch_bounds__(256) void attn_combine(const unsigned short* __restrict__ O0h,
                                                    const unsigned short* __restrict__ O1h,
                                                    const float* __restrict__ L0,
                                                    const float* __restrict__ L1,
                                                    unsigned short* __restrict__ Oh) {
    int t = blockIdx.x * blockDim.x + threadIdx.x;
    size_t e = (size_t)t * 8;
    int row = (int)(e >> 10);            // b*N + n
    int col = (int)(e & 1023);
    int h = col >> 6;
    int b = row >> 11, n = row & (N_ - 1);
    size_t lidx = (size_t)(b * H_ + h) * N_ + n;
    float inv = 1.0f / (L0[lidx] + L1[lidx]);
    short8 a = *(const short8*)(O0h + e);
    short8 c = *(const short8*)(O1h + e);
    short8 o;
#pragma unroll
    for (int j = 0; j < 8; ++j)
        o[j] = (short)f2h((h2f((unsigned short)a[j]) + h2f((unsigned short)c[j])) * inv);
    *(short8*)(Oh + e) = o;
}

// ---------------------------------------------------------------------------
extern "C" void kernel_launch(void* const* d_in, const int* in_sizes, int n_in,
                              void* d_out, int out_size, void* d_ws, size_t ws_size,
                              hipStream_t stream) {
    const float* x     = (const float*)d_in[0];
    const float* w_qkv = (const float*)d_in[1];
    const float* w_out = (const float*)d_in[2];
    const float* b_out = (const float*)d_in[3];
    float* out = (float*)d_out;

    unsigned short* Xh  = (unsigned short*)d_ws;     // 4M elems (reused as Oh)
    unsigned short* WqT = Xh + 4194304;              // 3M
    unsigned short* WoT = WqT + 3145728;             // 1M
    unsigned short* Qh  = WoT + 1048576;             // 4M
    unsigned short* Kh  = Qh + 4194304;              // 4M
    unsigned short* Vh  = Kh + 4194304;              // 4M
    unsigned short* O0h = Vh + 4194304;              // 4M
    unsigned short* O1h = O0h + 4194304;             // 4M
    float* L0 = (float*)(O1h + 4194304);             // 64K floats
    float* L1 = L0 + 65536;                          // 64K floats

    convert_all<<<dim3(3072), 256, 0, stream>>>(x, w_qkv, w_out, Xh, WqT, WoT);
    qkv_gemm_mfma<<<dim3(QKVC_ / 128, 32), 256, 0, stream>>>(Xh, WqT, Qh, Kh, Vh);
    attn_mfma<<<dim3(32, 32), 512, 0, stream>>>(Qh, Kh, Vh, O0h, O1h, L0, L1);
    attn_combine<<<dim3(2048), 256, 0, stream>>>(O0h, O1h, L0, L1, Xh);
    out_gemm_mfma<<<dim3(DIM_ / 64, 32), 256, 0, stream>>>(Xh, WoT, b_out, out);
}

// Round 25
// 112.280 us; speedup vs baseline: 2.0680x; 1.1080x over previous
//
#include <hip/hip_runtime.h>
#include <math.h>

#define B_    2
#define N_    2048
#define DIM_  1024
#define H_    16
#define D_    64
#define INNER_ 1024
#define QKVC_ 3072

typedef __attribute__((ext_vector_type(8))) short short8;
typedef __attribute__((ext_vector_type(4))) short short4v;
typedef __attribute__((ext_vector_type(4))) float f32x4;
typedef __attribute__((ext_vector_type(4))) float float4v;
typedef _Float16 half8 __attribute__((ext_vector_type(8)));
typedef __fp16 fp16v2 __attribute__((ext_vector_type(2)));

union h8u { short8 s; half8 h; fp16v2 h2[4]; };
static __device__ __forceinline__ half8 s2h(short8 s) { h8u u; u.s = s; return u.h; }

static __device__ __forceinline__ unsigned short f2h(float f) {
    _Float16 h = (_Float16)f;
    unsigned short u;
    __builtin_memcpy(&u, &h, 2);
    return u;
}

static __device__ __forceinline__ void gload16(const void* g, void* l) {
    __builtin_amdgcn_global_load_lds((__attribute__((address_space(1))) void*)(g),
                                     (__attribute__((address_space(3))) void*)(l),
                                     16, 0, 0);
}

// ---------------------------------------------------------------------------
// merged converts: blocks [0,2048) x->fp16; [2048,2816) w_qkv^T; [2816,3072) w_out^T
// ---------------------------------------------------------------------------
__global__ __launch_bounds__(256) void convert_all(const float* __restrict__ X,
                                                   const float* __restrict__ Wq,
                                                   const float* __restrict__ Wo,
                                                   unsigned short* __restrict__ Xh,
                                                   unsigned short* __restrict__ WqT,
                                                   unsigned short* __restrict__ WoT) {
    __shared__ unsigned short Sh[64][65];
    const int blk = blockIdx.x;
    const int tid = threadIdx.x;
    if (blk < 2048) {
        int t = blk * 256 + tid;
        size_t off = (size_t)t * 8;
        float4v a = *(const float4v*)(X + off);
        float4v b = *(const float4v*)(X + off + 4);
        short8 o;
#pragma unroll
        for (int j = 0; j < 4; ++j) {
            o[j]     = (short)f2h(a[j]);
            o[4 + j] = (short)f2h(b[j]);
        }
        *(short8*)(Xh + off) = o;
        return;
    }
    const float* W;
    unsigned short* T;
    int n0, k0, Nw;
    if (blk < 2816) {
        int g = blk - 2048;                 // 48 x 16
        W = Wq; T = WqT; Nw = QKVC_;
        n0 = (g % 48) * 64; k0 = (g / 48) * 64;
    } else {
        int g = blk - 2816;                 // 16 x 16
        W = Wo; T = WoT; Nw = DIM_;
        n0 = (g % 16) * 64; k0 = (g / 16) * 64;
    }
#pragma unroll
    for (int l = 0; l < 16; ++l) {
        int idx = tid + l * 256;
        int r = idx >> 6, c = idx & 63;
        Sh[c][r] = f2h(W[(size_t)(k0 + r) * Nw + n0 + c]);
    }
    __syncthreads();
#pragma unroll
    for (int l = 0; l < 16; ++l) {
        int idx = tid + l * 256;
        int r = idx >> 6, c = idx & 63;
        T[(size_t)(n0 + r) * 1024 + k0 + c] = Sh[r][c];
    }
}

// ---------------------------------------------------------------------------
// fp16 GEMM core, BK=64 (R20-proven): 128x128 tile, T2-swizzled LDS.
// ---------------------------------------------------------------------------
#define GEMM_STAGE64(gA, gB)                                                       \
    {                                                                              \
        int srow = lane >> 3;                                                      \
        int gsw  = ((lane & 7) ^ srow) * 8;                                        \
        _Pragma("unroll") for (int i_ = 0; i_ < 4; ++i_) {                         \
            gload16(gA + (size_t)(m0 + w * 32 + 8 * i_ + srow) * 1024 + k0 + gsw,  \
                    sA + (w * 32 + 8 * i_) * 64);                                  \
            gload16(gB + (size_t)(n0 + w * 32 + 8 * i_ + srow) * 1024 + k0 + gsw,  \
                    sB + (w * 32 + 8 * i_) * 64);                                  \
        }                                                                          \
    }

#define GEMM_BODY64()                                                              \
    half8 af[4][2], bf[4][2];                                                      \
    _Pragma("unroll") for (int f = 0; f < 4; ++f) {                                \
        int arow = (wr + f * 16 + (lane & 15)) * 64;                               \
        int brow = (wc + f * 16 + (lane & 15)) * 64;                               \
        _Pragma("unroll") for (int h = 0; h < 2; ++h) {                            \
            int g = (((lane >> 4) + 4 * h) ^ (lane & 7)) * 8;                      \
            af[f][h] = s2h(*(const short8*)&sA[arow + g]);                         \
            bf[f][h] = s2h(*(const short8*)&sB[brow + g]);                         \
        }                                                                          \
    }                                                                              \
    _Pragma("unroll") for (int i = 0; i < 4; ++i)                                  \
        _Pragma("unroll") for (int j = 0; j < 4; ++j) {                            \
            acc[i][j] = __builtin_amdgcn_mfma_f32_16x16x32_f16(af[i][0], bf[j][0], acc[i][j], 0, 0, 0); \
            acc[i][j] = __builtin_amdgcn_mfma_f32_16x16x32_f16(af[i][1], bf[j][1], acc[i][j], 0, 0, 0); \
        }

// XCD-aware bijective block remap (T1): nblk % 8 == 0 for both GEMM grids.
#define XCD_REMAP()                                                                \
    const int fblk = blockIdx.y * gridDim.x + blockIdx.x;                          \
    const int per_ = (gridDim.x * gridDim.y) >> 3;                                 \
    const int rf = (fblk & 7) * per_ + (fblk >> 3);                                \
    const int m0 = (rf / gridDim.x) * 128, n0 = (rf % gridDim.x) * 128;

// ---------------------------------------------------------------------------
// qkv GEMM with FUSED RoPE epilogue (native __sinf/__cosf only).
// ---------------------------------------------------------------------------
#define QSCALE 0.180336879963f   // 0.125 * log2(e)
__global__ __launch_bounds__(256) void qkv_gemm_mfma(const unsigned short* __restrict__ Ah,
                                                     const unsigned short* __restrict__ Bh,
                                                     unsigned short* __restrict__ Qh,
                                                     unsigned short* __restrict__ Kh,
                                                     unsigned short* __restrict__ Vh) {
    __shared__ __align__(16) unsigned short sA[8192], sB[8192];
    const int tid = threadIdx.x;
    const int lane = tid & 63, w = tid >> 6;
    const int wr = (w >> 1) * 64, wc = (w & 1) * 64;
    XCD_REMAP();
    f32x4 acc[4][4] = {};

    for (int k0 = 0; k0 < 1024; k0 += 64) {
        GEMM_STAGE64(Ah, Bh);
        __syncthreads();
        GEMM_BODY64();
        __syncthreads();
    }

    const int seg = n0 >> 10;            // whole block: 0=Q 1=K 2=V
    const int parity = lane & 1;

#pragma unroll
    for (int i = 0; i < 4; ++i) {
        int mbase = m0 + wr + i * 16 + (lane >> 4) * 4;
#pragma unroll
        for (int j = 0; j < 4; ++j) {
            int col = n0 + wc + j * 16 + (lane & 15);
            int wcol = col & 1023;
            int h = wcol >> 6, dd = wcol & 63;
            unsigned short* dst = (seg == 0) ? Qh : (seg == 1 ? Kh : Vh);
            if (seg == 2) {
#pragma unroll
                for (int r = 0; r < 4; ++r) {
                    int row = mbase + r;
                    int b = row >> 11, n = row & (N_ - 1);
                    dst[((size_t)(b * H_ + h) * N_ + n) * D_ + dd] = f2h(acc[i][j][r]);
                }
            } else {
                float freq = __builtin_amdgcn_exp2f((float)(dd >> 1) * -0.4152410118f);
#pragma unroll
                for (int r = 0; r < 4; ++r) {
                    int row = mbase + r;
                    int b = row >> 11, n = row & (N_ - 1);
                    float ang = (float)n * freq;
                    float s = __sinf(ang);
                    float c = __cosf(ang);
                    float val = acc[i][j][r];
                    float partner = __shfl_xor(val, 1);
                    float rot = parity ? (val * c + partner * s)
                                       : (val * c - partner * s);
                    if (seg == 0) rot *= QSCALE;
                    dst[((size_t)(b * H_ + h) * N_ + n) * D_ + dd] = f2h(rot);
                }
            }
        }
    }
}

// ---------------------------------------------------------------------------
// out projection GEMM, 128x64 tile (R22-proven; grid 16x32 = 2 blocks/CU).
// ---------------------------------------------------------------------------
__global__ __launch_bounds__(256) void out_gemm_mfma(const unsigned short* __restrict__ Ah,
                                                     const unsigned short* __restrict__ Bh,
                                                     const float* __restrict__ bias,
                                                     float* __restrict__ C) {
    __shared__ __align__(16) unsigned short sA[8192], sB[4096];
    const int tid = threadIdx.x;
    const int lane = tid & 63, w = tid >> 6;
    const int wr = w * 32;
    const int fblk = blockIdx.y * gridDim.x + blockIdx.x;
    const int per_ = (gridDim.x * gridDim.y) >> 3;
    const int rf = (fblk & 7) * per_ + (fblk >> 3);
    const int m0 = (rf / gridDim.x) * 128, n0 = (rf % gridDim.x) * 64;
    f32x4 acc[2][4] = {};

    for (int k0 = 0; k0 < 1024; k0 += 64) {
        {
            int srow = lane >> 3;
            int gsw  = ((lane & 7) ^ srow) * 8;
#pragma unroll
            for (int i_ = 0; i_ < 4; ++i_)
                gload16(Ah + (size_t)(m0 + w * 32 + 8 * i_ + srow) * 1024 + k0 + gsw,
                        sA + (w * 32 + 8 * i_) * 64);
            gload16(Bh + (size_t)(n0 + w * 8 + srow) * 1024 + k0 + gsw,
                    sB + (w * 8) * 64);
            gload16(Bh + (size_t)(n0 + 32 + w * 8 + srow) * 1024 + k0 + gsw,
                    sB + (32 + w * 8) * 64);
        }
        __syncthreads();
        {
            half8 af[2][2], bf[4][2];
#pragma unroll
            for (int f = 0; f < 2; ++f) {
                int arow = (wr + f * 16 + (lane & 15)) * 64;
#pragma unroll
                for (int h = 0; h < 2; ++h) {
                    int g = (((lane >> 4) + 4 * h) ^ (lane & 7)) * 8;
                    af[f][h] = s2h(*(const short8*)&sA[arow + g]);
                }
            }
#pragma unroll
            for (int j = 0; j < 4; ++j) {
                int brow = (j * 16 + (lane & 15)) * 64;
#pragma unroll
                for (int h = 0; h < 2; ++h) {
                    int g = (((lane >> 4) + 4 * h) ^ (lane & 7)) * 8;
                    bf[j][h] = s2h(*(const short8*)&sB[brow + g]);
                }
            }
#pragma unroll
            for (int i = 0; i < 2; ++i)
#pragma unroll
                for (int j = 0; j < 4; ++j) {
                    acc[i][j] = __builtin_amdgcn_mfma_f32_16x16x32_f16(af[i][0], bf[j][0], acc[i][j], 0, 0, 0);
                    acc[i][j] = __builtin_amdgcn_mfma_f32_16x16x32_f16(af[i][1], bf[j][1], acc[i][j], 0, 0, 0);
                }
        }
        __syncthreads();
    }

#pragma unroll
    for (int i = 0; i < 2; ++i) {
        int mbase = m0 + wr + i * 16 + (lane >> 4) * 4;
#pragma unroll
        for (int j = 0; j < 4; ++j) {
            int col = n0 + j * 16 + (lane & 15);
            float bv = bias[col];
#pragma unroll
            for (int r = 0; r < 4; ++r)
                C[(size_t)(mbase + r) * DIM_ + col] = acc[i][j][r] + bv;
        }
    }
}

// ---------------------------------------------------------------------------
// Flash attention v11 (R22-proven best, 53.0us): q-tile 256, one 1024-thread
// block; static-shift softmax, rotated pipeline, V 3-slot permuted ring,
// K LDS dbuf (gload_lds, XOR-swz), in-register P. Waves 0-7 stage.
// ---------------------------------------------------------------------------
#define PADV 72
#define NT   (N_ / 64)
__global__ __launch_bounds__(1024, 2) void attn_mfma(const unsigned short* __restrict__ Qh,
                                                     const unsigned short* __restrict__ Kh,
                                                     const unsigned short* __restrict__ Vh,
                                                     unsigned short* __restrict__ Oh) {
    __shared__ __align__(16) unsigned short Ks[2 * 64 * 64];    // K rows, XOR-swz cols
    __shared__ __align__(16) unsigned short Vt[3][64][PADV];    // permuted V^T ring
    const int tid = threadIdx.x;
    const int w = tid >> 6;          // 0..15
    const int l = tid & 63;
    const int lr = l & 15, lg = l >> 4;
    const bool stager = (tid < 512);

    // XCD remap: 256 blocks; xcd x owns bh in [4x, 4x+4)
    const int f = blockIdx.y * gridDim.x + blockIdx.x;          // 0..255
    const int x = f & 7, g = f >> 3;                            // g: 0..31
    const int bh = x * 4 + (g >> 3);
    const int q0 = (g & 7) * 256;
    const size_t base = (size_t)bh * N_ * D_;

    // K staging coords (threads 0-511; pre-swizzled source, linear LDS dest)
    const int srow = tid >> 3;           // 0..63 (for tid<512)
    const int scg  = tid & 7;
    const int gcg  = scg ^ (srow & 7);
    const unsigned short* ksrc = Kh + base + (size_t)srow * D_ + gcg * 8;
    unsigned short* kdst = Ks + w * 512; // valid for w<8

    // K fragment LDS offsets (loop-invariant)
    const int kb0 = lr * 64 + (lg ^ (lr & 7)) * 8;
    const int kb1 = lr * 64 + ((lg + 4) ^ (lr & 7)) * 8;

    // V staging coords (threads 0-511) + permuted column position
    const int sd0 = (tid & 15) * 4;
    const int skv = ((tid >> 4) & 31) * 2;
    const int vpos = ((skv >> 5) * 32) + (((skv >> 2) & 3) * 8) +
                     (((skv >> 4) & 1) * 4) + (skv & 3);

    // Q as B-operand: rows q0 + w*16 + lr
    const unsigned short* qrow = Qh + base + (size_t)(q0 + w * 16 + lr) * D_ + lg * 8;
    const half8 qf0 = s2h(*(const short8*)qrow);
    const half8 qf1 = s2h(*(const short8*)(qrow + 32));

    f32x4 oacc[4] = {};                 // [dt]: q=lg*4+r, d=dt*16+lr
    float lsum = 0.f;                   // per-lane partial lsum
    h8u pa_prev[2];                     // carried P fragments (tile ti-1)
    pa_prev[0].s = short8{0,0,0,0,0,0,0,0};
    pa_prev[1].s = short8{0,0,0,0,0,0,0,0};

    // ---- prologue: stage tile 0 (waves 0-7) ----
    if (stager) {
        gload16(ksrc, kdst);
        short4v r0 = *(const short4v*)(Vh + base + (size_t)(skv + 0) * D_ + sd0);
        short4v r1 = *(const short4v*)(Vh + base + (size_t)(skv + 1) * D_ + sd0);
#pragma unroll
        for (int j = 0; j < 4; ++j) {
            unsigned int pk = (unsigned int)(unsigned short)r0[j] |
                              ((unsigned int)(unsigned short)r1[j] << 16);
            *(unsigned int*)&Vt[0][sd0 + j][vpos] = pk;
        }
    }

    int rd = 2, cu = 0, wr_ = 1;        // V ring slots: (ti-1)%3, ti%3, (ti+1)%3

    for (int ti = 0; ti < NT; ++ti) {
        const int kcur = ti & 1, knxt = kcur ^ 1;
        __syncthreads();

        // ---- issue tile ti+1 staging early (waves 0-7) ----
        short4v n0v = {}, n1v = {};
        if (stager && ti + 1 < NT) {
            gload16(ksrc + (size_t)(ti + 1) * 64 * D_, kdst + knxt * 4096);
            const unsigned short* nsrc = Vh + base + (size_t)((ti + 1) * 64 + skv) * D_ + sd0;
            n0v = *(const short4v*)nsrc;
            n1v = *(const short4v*)(nsrc + D_);
        }

        // ---- MFMA cluster: QK(ti) then PV(ti-1) ----
        f32x4 sacc[4] = {};
        const unsigned short* kbuf = Ks + kcur * 4096;
        __builtin_amdgcn_s_setprio(1);
#pragma unroll
        for (int t = 0; t < 4; ++t) {
            half8 kf0 = s2h(*(const short8*)(kbuf + t * 1024 + kb0));
            half8 kf1 = s2h(*(const short8*)(kbuf + t * 1024 + kb1));
            sacc[t] = __builtin_amdgcn_mfma_f32_16x16x32_f16(kf0, qf0, sacc[t], 0, 0, 0);
            sacc[t] = __builtin_amdgcn_mfma_f32_16x16x32_f16(kf1, qf1, sacc[t], 0, 0, 0);
        }
        if (ti > 0) {
#pragma unroll
            for (int m2 = 0; m2 < 2; ++m2)
#pragma unroll
                for (int dt = 0; dt < 4; ++dt) {
                    half8 vf = s2h(*(const short8*)&Vt[rd][dt * 16 + lr][m2 * 32 + lg * 8]);
                    oacc[dt] = __builtin_amdgcn_mfma_f32_16x16x32_f16(pa_prev[m2].h, vf, oacc[dt], 0, 0, 0);
                }
        }
        __builtin_amdgcn_s_setprio(0);

        // ---- softmax(ti): static shift — P = exp2(s) directly ----
#pragma unroll
        for (int t = 0; t < 4; ++t) {
            float e0 = __builtin_amdgcn_exp2f(sacc[t][0]);
            float e1 = __builtin_amdgcn_exp2f(sacc[t][1]);
            float e2 = __builtin_amdgcn_exp2f(sacc[t][2]);
            float e3 = __builtin_amdgcn_exp2f(sacc[t][3]);
            lsum += (e0 + e1) + (e2 + e3);
            pa_prev[t >> 1].h2[(t & 1) * 2]     = __builtin_amdgcn_cvt_pkrtz(e0, e1);
            pa_prev[t >> 1].h2[(t & 1) * 2 + 1] = __builtin_amdgcn_cvt_pkrtz(e2, e3);
        }

        // ---- commit V(ti+1) into ring slot wr_ (waves 0-7) ----
        if (stager && ti + 1 < NT) {
#pragma unroll
            for (int j = 0; j < 4; ++j) {
                unsigned int pk = (unsigned int)(unsigned short)n0v[j] |
                                  ((unsigned int)(unsigned short)n1v[j] << 16);
                *(unsigned int*)&Vt[wr_][sd0 + j][vpos] = pk;
            }
        }
        int t_ = rd; rd = cu; cu = wr_; wr_ = t_;
    }

    // ---- epilogue: final PV(NT-1) (ring slot rd), then normalize ----
#pragma unroll
    for (int m2 = 0; m2 < 2; ++m2)
#pragma unroll
        for (int dt = 0; dt < 4; ++dt) {
            half8 vf = s2h(*(const short8*)&Vt[rd][dt * 16 + lr][m2 * 32 + lg * 8]);
            oacc[dt] = __builtin_amdgcn_mfma_f32_16x16x32_f16(pa_prev[m2].h, vf, oacc[dt], 0, 0, 0);
        }

    lsum += __shfl_xor(lsum, 16);
    lsum += __shfl_xor(lsum, 32);
    int b = bh >> 4, h = bh & 15;
#pragma unroll
    for (int r = 0; r < 4; ++r) {
        float ls = __shfl(lsum, lg * 4 + r);
        float inv = 1.0f / ls;
        size_t orow = ((size_t)b * N_ + q0 + w * 16 + lg * 4 + r) * INNER_ + h * 64 + lr;
#pragma unroll
        for (int dt = 0; dt < 4; ++dt)
            Oh[orow + 16 * dt] = f2h(oacc[dt][r] * inv);
    }
}

// ---------------------------------------------------------------------------
extern "C" void kernel_launch(void* const* d_in, const int* in_sizes, int n_in,
                              void* d_out, int out_size, void* d_ws, size_t ws_size,
                              hipStream_t stream) {
    const float* x     = (const float*)d_in[0];
    const float* w_qkv = (const float*)d_in[1];
    const float* w_out = (const float*)d_in[2];
    const float* b_out = (const float*)d_in[3];
    float* out = (float*)d_out;

    unsigned short* Xh  = (unsigned short*)d_ws;     // 4M elems (reused as Oh)
    unsigned short* WqT = Xh + 4194304;              // 3M
    unsigned short* WoT = WqT + 3145728;             // 1M
    unsigned short* Qh  = WoT + 1048576;             // 4M
    unsigned short* Kh  = Qh + 4194304;              // 4M
    unsigned short* Vh  = Kh + 4194304;              // 4M

    convert_all<<<dim3(3072), 256, 0, stream>>>(x, w_qkv, w_out, Xh, WqT, WoT);
    qkv_gemm_mfma<<<dim3(QKVC_ / 128, 32), 256, 0, stream>>>(Xh, WqT, Qh, Kh, Vh);
    attn_mfma<<<dim3(8, 32), 1024, 0, stream>>>(Qh, Kh, Vh, Xh);
    out_gemm_mfma<<<dim3(DIM_ / 64, 32), 256, 0, stream>>>(Xh, WoT, b_out, out);
}